// Round 3
// baseline (199.650 us; speedup 1.0000x reference)
//
#include <hip/hip_runtime.h>
#include <hip/hip_bf16.h>

typedef __attribute__((ext_vector_type(8))) short short8;
typedef __attribute__((ext_vector_type(16))) float f32x16;
typedef __attribute__((ext_vector_type(4))) unsigned uint4v;
typedef unsigned int u32;

#define D_DIM 128
#define G_DIM 9
#define O_DIM 128
#define K_DIM 1152
#define BROWS 256
#define INV2PI 0.15915494309189535f

__device__ __forceinline__ short f2bf(float f) {
  unsigned u = __float_as_uint(f);
  unsigned r = (u + 0x7FFFu + ((u >> 16) & 1u)) >> 16;
  return (short)r;
}

__device__ __forceinline__ float bf2f(short s) {
  return __uint_as_float(((unsigned)(unsigned short)s) << 16);
}

__device__ __forceinline__ unsigned pk2bf(float a, float b) {
  __hip_bfloat162 h = __float22bfloat162_rn(float2{a, b});
  return *reinterpret_cast<unsigned*>(&h);
}

// Prep:
//  Bp (ws): 9 chunks x 128 o x 128 d bf16, row byte-swizzled: short index d ^ ((o&7)<<3)
//  pt2 (ws): [g][d] = phase[d][g] / 2pi
//  fq2 (ws): freq[g] / 2pi
__global__ void sinekan_prep(const float* __restrict__ amp,
                             const float* __restrict__ phase,
                             const float* __restrict__ freq,
                             short* __restrict__ Bp,
                             float* __restrict__ pt2,
                             float* __restrict__ fq2) {
  int i = blockIdx.x * blockDim.x + threadIdx.x;
  if (i < G_DIM * O_DIM * D_DIM) {
    int g = i >> 14, rem = i & 16383, o = rem >> 7, d = rem & 127;
    Bp[(g << 14) + (o << 7) + (d ^ ((o & 7) << 3))] = f2bf(amp[(o * D_DIM + d) * G_DIM + g]);
  }
  if (i < K_DIM) {
    int g = i >> 7, d = i & 127;
    pt2[i] = phase[d * G_DIM + g] * INV2PI;
  }
  if (i < G_DIM) fq2[i] = freq[i] * INV2PI;
}

__device__ __forceinline__ void stage_b(const short* __restrict__ Bp, short* dst_lds,
                                        int g, int tid) {
  // linear copy of pre-swizzled source; wave wv covers [wv*1024 + c*4096, +1KB)
  const char* src = (const char*)Bp + ((size_t)g << 15) + tid * 16;
  char* dst = (char*)dst_lds + (tid >> 6) * 1024;
#pragma unroll
  for (int c = 0; c < 8; ++c) {
    __builtin_amdgcn_global_load_lds(
        (const __attribute__((address_space(1))) u32*)(src + c * 4096),
        (__attribute__((address_space(3))) u32*)(dst + c * 4096), 16, 0, 0);
  }
}

__global__ __launch_bounds__(256, 2)
void sinekan_fused(const float* __restrict__ x,
                   const int* __restrict__ mask,
                   const float* __restrict__ bias,
                   const float* __restrict__ lnw,
                   const float* __restrict__ lnb,
                   const short* __restrict__ Bp,
                   const float* __restrict__ pt2,
                   const float* __restrict__ fq2,
                   float* __restrict__ out) {
  __shared__ short b_lds[2][O_DIM * D_DIM];   // 2 x 32 KB, swizzled rows of 256B
  __shared__ float pt_lds[G_DIM * D_DIM];     // 4.6 KB
  __shared__ float mu_s[BROWS], rs_s[BROWS], mk_s[BROWS];
  __shared__ float w_s[D_DIM], bb_s[D_DIM];

  const int tid = threadIdx.x;
  const int row0 = blockIdx.x * BROWS;
  const int wv = tid >> 6, lane = tid & 63, lr = lane & 31, hi = lane >> 5;

  // issue B chunk 0 immediately — overlaps with all of init/stats
  stage_b(Bp, b_lds[0], 0, tid);

  if (tid < D_DIM) { w_s[tid] = lnw[tid]; bb_s[tid] = lnb[tid]; }
  mk_s[tid] = mask[row0 + tid] ? 1.0f : 0.0f;
  for (int i = tid; i < G_DIM * D_DIM; i += 256) pt_lds[i] = pt2[i];

  // ---- LN stats: 16 lanes per row, coalesced ----
  {
    int rloc = tid >> 4, ch = tid & 15;
#pragma unroll 1
    for (int it = 0; it < 16; ++it) {
      int r = it * 16 + rloc;
      const float4* xp = (const float4*)(x + (size_t)(row0 + r) * D_DIM + ch * 8);
      float4 a = xp[0], b = xp[1];
      float s  = a.x + a.y + a.z + a.w + b.x + b.y + b.z + b.w;
      float sq = a.x*a.x + a.y*a.y + a.z*a.z + a.w*a.w
               + b.x*b.x + b.y*b.y + b.z*b.z + b.w*b.w;
#pragma unroll
      for (int off = 1; off < 16; off <<= 1) {
        s  += __shfl_xor(s, off, 64);
        sq += __shfl_xor(sq, off, 64);
      }
      if (ch == 0) {
        float m = s * (1.0f / 128.0f);
        mu_s[r] = m;
        rs_s[r] = rsqrtf(sq * (1.0f / 128.0f) - m * m + 1e-5f);
      }
    }
  }
  __syncthreads();   // stats ready (also drains stage(0) — harmless)

  // ---- cache xn (LN output incl. weight/bias) as bf16 pairs: 64 VGPR ----
  short8 xnc[2][8];
#pragma unroll
  for (int m = 0; m < 2; ++m) {
    const int rl = wv * 64 + m * 32 + lr;
    const float mu = mu_s[rl], rs = rs_s[rl];
    const float* xr = x + (size_t)(row0 + rl) * D_DIM;
#pragma unroll
    for (int kk = 0; kk < 8; ++kk) {
      const int d0 = kk * 16 + hi * 8;
      float4 xa = *(const float4*)(xr + d0);
      float4 xb = *(const float4*)(xr + d0 + 4);
      float xv[8] = {xa.x, xa.y, xa.z, xa.w, xb.x, xb.y, xb.z, xb.w};
      uint4v pk;
#pragma unroll
      for (int jj = 0; jj < 4; ++jj) {
        float e0 = (xv[2*jj]   - mu) * rs * w_s[d0 + 2*jj]   + bb_s[d0 + 2*jj];
        float e1 = (xv[2*jj+1] - mu) * rs * w_s[d0 + 2*jj+1] + bb_s[d0 + 2*jj+1];
        pk[jj] = pk2bf(e0, e1);
      }
      xnc[m][kk] = __builtin_bit_cast(short8, pk);
    }
  }
  __syncthreads();   // b_lds[0] staged & drained

  const int swz = (lr & 7) << 4;            // read-side XOR (bytes), matches prep
  f32x16 acc[2][4] = {};

#pragma unroll 1
  for (int g = 0; g < G_DIM; ++g) {
    if (g + 1 < G_DIM) stage_b(Bp, b_lds[(g + 1) & 1], g + 1, tid);  // flies under kk-loop
    const float fg2v = fq2[g];
    const short* bl = b_lds[g & 1];
    const float* ptg = pt_lds + (g << 7);

#pragma unroll
    for (int kk = 0; kk < 8; ++kk) {
      const int d0 = kk * 16 + hi * 8;
      float4 p0 = *(const float4*)(ptg + d0);
      float4 p1 = *(const float4*)(ptg + d0 + 4);
      const float ph[8] = {p0.x, p0.y, p0.z, p0.w, p1.x, p1.y, p1.z, p1.w};

      short8 af[2];
#pragma unroll
      for (int m = 0; m < 2; ++m) {
        uint4v pk;
#pragma unroll
        for (int jj = 0; jj < 4; ++jj) {
          float a0 = fmaf(bf2f(xnc[m][kk][2*jj]),     fg2v, ph[2*jj]);
          float a1 = fmaf(bf2f(xnc[m][kk][2*jj + 1]), fg2v, ph[2*jj + 1]);
          float s0 = __builtin_amdgcn_sinf(a0);
          float s1 = __builtin_amdgcn_sinf(a1);
          pk[jj] = pk2bf(s0, s1);
        }
        af[m] = __builtin_bit_cast(short8, pk);
      }

      const int kx = (kk * 32 + hi * 16) ^ swz;   // byte offset in row
      short8 bf[4];
#pragma unroll
      for (int n = 0; n < 4; ++n)
        bf[n] = *(const short8*)((const char*)bl + (((n * 32 + lr) << 8) + kx));

#pragma unroll
      for (int m = 0; m < 2; ++m)
#pragma unroll
        for (int n = 0; n < 4; ++n)
          acc[m][n] = __builtin_amdgcn_mfma_f32_32x32x16_bf16(af[m], bf[n], acc[m][n], 0, 0, 0);
    }
    __syncthreads();  // drains next-chunk staging; b_lds[g&1] free for g+2
  }

  // ---- epilogue: + bias, * mask ----
#pragma unroll
  for (int m = 0; m < 2; ++m) {
#pragma unroll
    for (int n = 0; n < 4; ++n) {
      int col = n * 32 + lr;
      float bv = bias[col];
#pragma unroll
      for (int reg = 0; reg < 16; ++reg) {
        int rit  = (reg & 3) + 8 * (reg >> 2) + 4 * hi;
        int rloc = wv * 64 + m * 32 + rit;
        out[(size_t)(row0 + rloc) * O_DIM + col] = (acc[m][n][reg] + bv) * mk_s[rloc];
      }
    }
  }
}

extern "C" void kernel_launch(void* const* d_in, const int* in_sizes, int n_in,
                              void* d_out, int out_size, void* d_ws, size_t ws_size,
                              hipStream_t stream) {
  const float* x    = (const float*)d_in[0];
  const int* mk     = (const int*)d_in[1];
  const float* freq = (const float*)d_in[2];
  const float* phase= (const float*)d_in[3];
  const float* amp  = (const float*)d_in[4];
  const float* bias = (const float*)d_in[5];
  const float* lnw  = (const float*)d_in[6];
  const float* lnb  = (const float*)d_in[7];
  float* out = (float*)d_out;

  int N = in_sizes[0] / D_DIM;                 // 131072 rows
  short* Bp = (short*)d_ws;                    // 294912 B swizzled bf16
  float* pt2 = (float*)((char*)d_ws + (size_t)G_DIM * O_DIM * D_DIM * sizeof(short));
  float* fq2 = pt2 + G_DIM * D_DIM;

  int total = G_DIM * O_DIM * D_DIM;           // 147456
  sinekan_prep<<<(total + 255) / 256, 256, 0, stream>>>(amp, phase, freq, Bp, pt2, fq2);
  sinekan_fused<<<N / BROWS, 256, 0, stream>>>(x, mk, bias, lnw, lnb, Bp, pt2, fq2, out);
}